// Round 3
// baseline (217.457 us; speedup 1.0000x reference)
//
#include <hip/hip_runtime.h>

#define TILE 16
#define RR 8
#define ND 17          // 2r+1 displacements per axis
#define PW 544         // padded dst width/height (512 + 2*16)
#define PPAD 16
#define HH 512
#define WW 512
#define CC 3
#define BB 4

// float4 load with only 4-byte alignment guarantee (global_load_dwordx4 is
// legal at dword alignment on CDNA).
typedef float f4a __attribute__((ext_vector_type(4), aligned(4)));

// ---------------- kernel 1: zero-padded dst copy into workspace ------------
__global__ __launch_bounds__(256) void pad_kernel(const float* __restrict__ dst,
                                                  float* __restrict__ P) {
    const int gpr = PW / 4;          // 136 float4 groups per row
    const int gpi = PW * gpr;        // per image-channel
    int idx = blockIdx.x * 256 + threadIdx.x;
    if (idx >= BB * CC * gpi) return;
    int bc  = idx / gpi;
    int rem = idx - bc * gpi;
    int y   = rem / gpr;
    int x   = (rem - y * gpr) * 4;
    float4 v = make_float4(0.f, 0.f, 0.f, 0.f);
    if (y >= PPAD && y < PPAD + HH && x >= PPAD && x < PPAD + WW)
        v = *(const float4*)(dst + ((size_t)bc * HH + (y - PPAD)) * WW + (x - PPAD));
    *(float4*)(P + ((size_t)bc * PW + y) * PW + x) = v;
}

// butterfly-add partner via ds_swizzle (LDS pipe; xor mask < 32)
template <int MASK>
__device__ __forceinline__ float swz_add(float x) {
    int y = __builtin_amdgcn_ds_swizzle(__float_as_int(x), (MASK << 10) | 0x1F);
    return x + __int_as_float(y);
}

// ---------------- kernel 2: per-tile SAD + argmin + gather, fused ----------
// block = 256 thr (4 waves) per tile. Wave w computes dy = w, w+4, w+8, ...
// Lane l: h = l>>5 (dx half: 0..8 / 8..16), jg = (l>>4)&1 (j half),
// i = l&15 (row). Each lane keeps 9 dx-accumulators over its 8-j segment;
// full sums emerge from a 5-stage ds_swizzle butterfly over lane bits 0..4.
__global__ __launch_bounds__(256, 4) void tile_kernel(const float* __restrict__ src,
                                                      const float* __restrict__ P,
                                                      const int* __restrict__ offset,
                                                      float* __restrict__ out) {
    __shared__ float costL[ND * 20];   // [dy][dx] rows padded to 20
    __shared__ int bestLDS;

    const int bid  = blockIdx.x;
    const int tile = ((bid & 7) << 9) | (bid >> 3);  // XCD-banding swizzle
    const int b  = tile >> 10;
    const int th = (tile >> 5) & 31;
    const int tw = tile & 31;
    const int ti = th * TILE, tj = tw * TILE;
    const int oy = offset[(b * 2 + 0) * 1024 + th * 32 + tw];
    const int ox = offset[(b * 2 + 1) * 1024 + th * 32 + tw];

    const int t  = threadIdx.x;
    const int wv = t >> 6;
    const int l  = t & 63;
    const int h  = l >> 5;
    const int jg = (l >> 4) & 1;
    const int i  = l & 15;

    // hoisted src fragment: S[c][jl], row ti+i, cols tj+8*jg .. +7 (16B aligned)
    float S[CC][8];
    #pragma unroll
    for (int c = 0; c < CC; ++c) {
        const float* sp = src + ((size_t)((b * CC + c) * HH + ti + i)) * WW + tj + 8 * jg;
        f4a v0 = *(const f4a*)sp;
        f4a v1 = *(const f4a*)(sp + 4);
        S[c][0] = v0.x; S[c][1] = v0.y; S[c][2] = v0.z; S[c][3] = v0.w;
        S[c][4] = v1.x; S[c][5] = v1.y; S[c][6] = v1.z; S[c][7] = v1.w;
    }

    const int cg = tj + ox + 8 + 8 * h + 8 * jg;  // window col base (4B aligned)
    const int r0 = ti + oy + 8 + i;               // window row for dy=0

    for (int dy = wv; dy < ND; dy += 4) {
        float acc[9];
        #pragma unroll
        for (int a = 0; a < 9; ++a) acc[a] = 0.f;

        #pragma unroll
        for (int c = 0; c < CC; ++c) {
            const float* wp = P + ((size_t)((b * CC + c) * PW + r0 + dy)) * PW + cg;
            f4a w0 = *(const f4a*)(wp + 0);
            f4a w1 = *(const f4a*)(wp + 4);
            f4a w2 = *(const f4a*)(wp + 8);
            f4a w3 = *(const f4a*)(wp + 12);
            float W[16] = { w0.x, w0.y, w0.z, w0.w, w1.x, w1.y, w1.z, w1.w,
                            w2.x, w2.y, w2.z, w2.w, w3.x, w3.y, w3.z, w3.w };
            #pragma unroll
            for (int a = 0; a < 9; ++a) {
                float s0 = acc[a];
                #pragma unroll
                for (int jl = 0; jl < 8; ++jl)
                    s0 += fabsf(W[a + jl] - S[c][jl]);
                acc[a] = s0;
            }
        }

        // sum over lane bits 0..4 (i and jg) — LDS-pipe swizzles + VALU adds
        #pragma unroll
        for (int a = 0; a < 9; ++a) {
            float x = acc[a];
            x = swz_add<1>(x);
            x = swz_add<2>(x);
            x = swz_add<4>(x);
            x = swz_add<8>(x);
            x = swz_add<16>(x);
            acc[a] = x;
        }
        if ((l & 31) == 0) {           // lane 0 of each h-group
            float* cp = &costL[dy * 20 + h * 8];   // h0 -> dx 0..8, h1 -> dx 8..16
            #pragma unroll
            for (int a = 0; a < 9; ++a) cp[a] = acc[a];
        }
    }
    __syncthreads();

    // ---- argmin over 289 costs (wave 0), tie -> smallest d ----
    if (t < 64) {
        float bc = 3.4e38f;
        int   bi = 0;
        for (int e = t; e < ND * ND; e += 64) {   // ascending: strict < keeps smallest
            int edy = e / ND;
            int edx = e - edy * ND;
            float cv = costL[edy * 20 + edx];
            if (cv < bc) { bc = cv; bi = e; }
        }
        #pragma unroll
        for (int m = 1; m <= 32; m <<= 1) {
            float oc = __shfl_xor(bc, m);
            int   oi = __shfl_xor(bi, m);
            if (oc < bc || (oc == bc && oi < bi)) { bc = oc; bi = oi; }
        }
        if (t == 0) {
            bestLDS = bi;
            int bdy = bi / ND;
            int bdx = bi - bdy * ND;
            out[(b * 2 + 0) * 1024 + th * 32 + tw] = (float)(oy + bdy - RR);
            out[(b * 2 + 1) * 1024 + th * 32 + tw] = (float)(ox + bdx - RR);
        }
    }
    __syncthreads();

    const int bi2 = bestLDS;
    const int bdy = bi2 / ND;
    const int bdx = bi2 - bdy * ND;
    float* aligned = out + BB * 2 * 1024;
    const int pr = ti + oy + bdy + 8;
    const int pc = tj + ox + bdx + 8;
    #pragma unroll
    for (int k = 0; k < 3; ++k) {
        int idx = t + 256 * k;          // 0..767 -> (c, ii, jj)
        int c  = idx >> 8;
        int ii = (idx >> 4) & 15;
        int jj = idx & 15;
        aligned[((size_t)((b * CC + c) * HH + ti + ii)) * WW + tj + jj] =
            P[((size_t)((b * CC + c) * PW + pr + ii)) * PW + pc + jj];
    }
}

extern "C" void kernel_launch(void* const* d_in, const int* in_sizes, int n_in,
                              void* d_out, int out_size, void* d_ws, size_t ws_size,
                              hipStream_t stream) {
    const float* src    = (const float*)d_in[0];
    const float* dst    = (const float*)d_in[1];
    const int*   offset = (const int*)d_in[2];
    float*       out    = (float*)d_out;

    float* P = (float*)d_ws;                         // 12*544*544 floats = 14.2 MB

    const int pad_groups = BB * CC * PW * (PW / 4);  // 887808
    pad_kernel<<<dim3((pad_groups + 255) / 256), 256, 0, stream>>>(dst, P);
    tile_kernel<<<dim3(BB * 1024), 256, 0, stream>>>(src, P, offset, out);
}